// Round 14
// baseline (262.210 us; speedup 1.0000x reference)
//
#include <hip/hip_runtime.h>

#define BATCH 4096
#define N 64

// One DPP unsigned-max step: x = max(x, dpp_move(x)). VALU only.
template<int CTRL>
__device__ __forceinline__ unsigned dpp_umax(unsigned x) {
    unsigned moved = (unsigned)__builtin_amdgcn_update_dpp(0, (int)x, CTRL, 0xf, 0xf, true);
    return (moved > x) ? moved : x;
}

// Broadcast float from wave-uniform lane ps via v_readlane (SGPR result).
// Used ONLY on latency-critical, once-per-step values (pv, u1, argmax result):
// r12 audit shows readlane costs ~8 cyc in throughput regime -> keep it off
// the bulk path.
__device__ __forceinline__ float lanebcastf(float v, int ps) {
    return __uint_as_float(__builtin_amdgcn_readlane(__float_as_uint(v), ps));
}

// Bulk broadcast via ds_bpermute (LDS pipe, overlaps the VALU fma stream;
// all bulk shuffles are independent -> throughput regime, latency hidden).
__device__ __forceinline__ float shflf(float v, int ps) {
    return __shfl(v, ps, 64);
}

// Packed-key argmax over live lanes: key = (bits(|col|) & ~63) | lane is
// monotone in |col| for floats >= 0 -> one umax tree + one readlane yields
// max AND pivot lane (wave-uniform).
__device__ __forceinline__ int pivot_argmax(float col, bool alive, int lane) {
    unsigned t = (__float_as_uint(col) & 0x7FFFFFC0u) | (unsigned)lane;
    unsigned r = alive ? t : 0u;
    r = dpp_umax<0x111>(r);   // row_shr:1
    r = dpp_umax<0x112>(r);   // row_shr:2
    r = dpp_umax<0x114>(r);   // row_shr:4
    r = dpp_umax<0x118>(r);   // row_shr:8
    r = dpp_umax<0x142>(r);   // row_bcast:15
    r = dpp_umax<0x143>(r);   // row_bcast:31
    return (int)(((unsigned)__builtin_amdgcn_readlane((int)r, 63)) & 63u);
}

// One elimination step with SHIFT-RENAMING: current pivot column is src[0];
// result written shifted (dst[j-1] = src[j] - m*u_j) so the next pivot
// column is dst[0]. All register indices compile-time; the k-loop ROLLS.
// W = max source column index updated this step. Updates past the live
// range hit garbage columns that are never read (validated r12, absmax 0).
template<int W>
__device__ __forceinline__ void lu_step(float (&src)[N], float (&dst)[N],
                                        int &ps, bool &alive,
                                        unsigned long long &chosen, int &inv,
                                        unsigned &sbits, float &l2sum,
                                        int lane)
{
    // bookkeeping for the current pivot (column src[0], lane ps)
    inv += __popcll(chosen >> ps);
    chosen |= (1ull << ps);
    alive = alive && (lane != ps);

    const float pv = lanebcastf(src[0], ps);   // m-critical path: readlane
    sbits ^= __float_as_uint(pv) & 0x80000000u;
    l2sum += __log2f(__builtin_fabsf(pv));

    // dead/pivot lanes free-run on garbage; safe: each pivot-row elem is
    // broadcast before its owner's fma overwrites it, and dead rows are
    // never selected again.
    const float m = src[0] * __builtin_amdgcn_rcpf(pv);

    // lookahead: produce next pivot column dst[0] first, start its argmax
    {
        const float uv = lanebcastf(src[1], ps);  // ps_next-critical: readlane
        dst[0] = __builtin_fmaf(-m, uv, src[1]);
    }
    const int ps_next = pivot_argmax(dst[0], alive, lane);

    // bulk trailing update: broadcasts on the LDS pipe (ds_bpermute),
    // fmas on the VALU pipe -- the two streams overlap.
    #pragma unroll
    for (int j = 2; j <= W; ++j) {
        const float uv = shflf(src[j], ps);
        dst[j - 1] = __builtin_fmaf(-m, uv, src[j]);
    }
    ps = ps_next;
}

// 16 steps at fixed compile-time width W, ROLLED (8 ping-pong pairs).
template<int W>
__device__ __forceinline__ void lu_block16(float (&a)[N], float (&b)[N],
                                           int &ps, bool &alive,
                                           unsigned long long &chosen, int &inv,
                                           unsigned &sbits, float &l2sum,
                                           int lane)
{
    #pragma unroll 1
    for (int t = 0; t < 8; ++t) {
        lu_step<W>(a, b, ps, alive, chosen, inv, sbits, l2sum, lane);
        lu_step<W>(b, a, ps, alive, chosen, inv, sbits, l2sum, lane);
    }
}

// Round 14: r12 base (rolled shift-rename, 118.5us) with the bulk broadcast
// moved from v_readlane (VALU, ~8cyc measured-by-subtraction) to
// ds_bpermute (LDS pipe, overlapped). Single-variable pipe-switch probe.
__global__ __launch_bounds__(64) void restricted_det_kernel(
    const float* __restrict__ U,
    const int* __restrict__ idx_up,
    const int* __restrict__ idx_dn,
    float* __restrict__ out)
{
    const int lane = threadIdx.x;      // 0..63, one wave per block
    const int wid  = blockIdx.x;       // sample id

    const int site0 = idx_up[wid * N + lane];
    const int site1 = idx_dn[wid * N + lane];

    float l2sum = 0.0f;                // sum log2|pivot| over both dets
    unsigned sbits = 0u;               // xor of pivot sign bits (uniform)
    int inv = 0;                       // inversion count (uniform)

    #pragma unroll 1
    for (int spin = 0; spin < 2; ++spin) {
        const int site = (spin == 0) ? site0 : site1;

        // lane i holds row i of the gathered matrix, in registers
        float a[N], b[N];
        {
            const float4* __restrict__ row =
                reinterpret_cast<const float4*>(U + (long)site * N);
            #pragma unroll
            for (int q = 0; q < N / 4; ++q) {
                float4 v = row[q];
                a[4*q+0]=v.x; a[4*q+1]=v.y; a[4*q+2]=v.z; a[4*q+3]=v.w;
            }
        }

        unsigned long long chosen = 0ull;
        bool alive = true;

        // prologue: pivot for step 0
        int ps = pivot_argmax(a[0], alive, lane);

        // 64 steps = 4 rolled blocks of 16, widths shrink 63/47/31/15
        lu_block16<63>(a, b, ps, alive, chosen, inv, sbits, l2sum, lane);
        lu_block16<47>(a, b, ps, alive, chosen, inv, sbits, l2sum, lane);
        lu_block16<31>(a, b, ps, alive, chosen, inv, sbits, l2sum, lane);
        lu_block16<15>(a, b, ps, alive, chosen, inv, sbits, l2sum, lane);
    }

    if (lane == 0) {
        const float sgn =
            (((sbits >> 31) ^ ((unsigned)inv & 1u)) != 0u) ? -1.0f : 1.0f;
        out[wid] = sgn;                                        // sign_up * sign_dn
        out[BATCH + wid] = l2sum * 0.69314718055994530942f;    // ln from log2
    }
}

extern "C" void kernel_launch(void* const* d_in, const int* in_sizes, int n_in,
                              void* d_out, int out_size, void* d_ws, size_t ws_size,
                              hipStream_t stream) {
    const float* U      = (const float*)d_in[0];
    const int*   idx_up = (const int*)d_in[1];
    const int*   idx_dn = (const int*)d_in[2];
    float* out = (float*)d_out;

    dim3 block(64);                  // one wave per block, 1 sample per wave
    dim3 grid(BATCH);                // 4096 waves, exact cover
    hipLaunchKernelGGL(restricted_det_kernel, grid, block, 0, stream,
                       U, idx_up, idx_dn, out);
}

// Round 15
// 167.877 us; speedup vs baseline: 1.5619x; 1.5619x over previous
//
#include <hip/hip_runtime.h>

#define BATCH 4096
#define N 64

// One DPP unsigned-max step: x = max(x, dpp_move(x)). VALU only.
template<int CTRL>
__device__ __forceinline__ unsigned dpp_umax(unsigned x) {
    unsigned moved = (unsigned)__builtin_amdgcn_update_dpp(0, (int)x, CTRL, 0xf, 0xf, true);
    return (moved > x) ? moved : x;
}

// Broadcast float from wave-uniform lane ps via v_readlane (SGPR result).
__device__ __forceinline__ float lanebcastf(float v, int ps) {
    return __uint_as_float(__builtin_amdgcn_readlane(__float_as_uint(v), ps));
}

// Packed-key argmax over live lanes: key = (bits(|col|) & ~63) | lane is
// monotone in |col| for floats >= 0 -> one umax tree + one readlane yields
// max AND pivot lane (wave-uniform).
__device__ __forceinline__ int pivot_argmax(float col, bool alive, int lane) {
    unsigned t = (__float_as_uint(col) & 0x7FFFFFC0u) | (unsigned)lane;
    unsigned r = alive ? t : 0u;
    r = dpp_umax<0x111>(r);   // row_shr:1
    r = dpp_umax<0x112>(r);   // row_shr:2
    r = dpp_umax<0x114>(r);   // row_shr:4
    r = dpp_umax<0x118>(r);   // row_shr:8
    r = dpp_umax<0x142>(r);   // row_bcast:15
    r = dpp_umax<0x143>(r);   // row_bcast:31
    return (int)(((unsigned)__builtin_amdgcn_readlane((int)r, 63)) & 63u);
}

// One elimination step with SHIFT-RENAMING: pivot column is src[0]; result
// written shifted (dst[j-1] = src[j] - m*u_j) so next pivot col is dst[0].
// Bulk broadcasts are BATCHED 4-WIDE: 4 independent v_readlane into 4
// distinct SGPRs, then the 4 consuming fmas. Producer->consumer distance
// >=4 instrs clears the CDNA "VALU writes SGPR -> VALU reads SGPR as
// constant" hazard wait-states that r12's pairwise order ate on every
// element (r12 audit: ~455 cyc/step vs ~206 ideal; excess / 39 elems
// ~= 4-5 cyc = the hazard).
template<int W>
__device__ __forceinline__ void lu_step(float (&src)[N], float (&dst)[N],
                                        int &ps, bool &alive,
                                        unsigned long long &chosen, int &inv,
                                        unsigned &sbits, float &l2sum,
                                        int lane)
{
    // bookkeeping for the current pivot (column src[0], lane ps)
    inv += __popcll(chosen >> ps);
    chosen |= (1ull << ps);
    alive = alive && (lane != ps);

    const float pv = lanebcastf(src[0], ps);
    sbits ^= __float_as_uint(pv) & 0x80000000u;
    l2sum += __log2f(__builtin_fabsf(pv));

    // dead/pivot lanes free-run on garbage; safe: each pivot-row elem is
    // broadcast before its owner's fma overwrites it, and dead rows are
    // never selected again.
    const float m = src[0] * __builtin_amdgcn_rcpf(pv);

    // lookahead: produce next pivot column dst[0] first, start its argmax
    {
        const float uv = lanebcastf(src[1], ps);
        dst[0] = __builtin_fmaf(-m, uv, src[1]);
    }
    const int ps_next = pivot_argmax(dst[0], alive, lane);

    // bulk trailing update, 4-wide readlane batches (hazard-free spacing)
    int j = 2;
    #pragma unroll
    for (; j + 3 <= W; j += 4) {
        const float u0 = lanebcastf(src[j + 0], ps);
        const float u1 = lanebcastf(src[j + 1], ps);
        const float u2 = lanebcastf(src[j + 2], ps);
        const float u3 = lanebcastf(src[j + 3], ps);
        dst[j - 1] = __builtin_fmaf(-m, u0, src[j + 0]);
        dst[j + 0] = __builtin_fmaf(-m, u1, src[j + 1]);
        dst[j + 1] = __builtin_fmaf(-m, u2, src[j + 2]);
        dst[j + 2] = __builtin_fmaf(-m, u3, src[j + 3]);
    }
    #pragma unroll
    for (; j <= W; ++j) {   // tail (always 2 elements for W=63/47/31/15)
        const float uv = lanebcastf(src[j], ps);
        dst[j - 1] = __builtin_fmaf(-m, uv, src[j]);
    }
    ps = ps_next;
}

// 16 steps at fixed compile-time width W, ROLLED (8 ping-pong pairs).
template<int W>
__device__ __forceinline__ void lu_block16(float (&a)[N], float (&b)[N],
                                           int &ps, bool &alive,
                                           unsigned long long &chosen, int &inv,
                                           unsigned &sbits, float &l2sum,
                                           int lane)
{
    #pragma unroll 1
    for (int t = 0; t < 8; ++t) {
        lu_step<W>(a, b, ps, alive, chosen, inv, sbits, l2sum, lane);
        lu_step<W>(b, a, ps, alive, chosen, inv, sbits, l2sum, lane);
    }
}

// Round 15: r12 base (rolled shift-rename, 118.5us, VALU 82%) with ONLY the
// j-loop readlanes batched 4-wide to clear the SGPR-write->read hazard.
__global__ __launch_bounds__(64) void restricted_det_kernel(
    const float* __restrict__ U,
    const int* __restrict__ idx_up,
    const int* __restrict__ idx_dn,
    float* __restrict__ out)
{
    const int lane = threadIdx.x;      // 0..63, one wave per block
    const int wid  = blockIdx.x;       // sample id

    const int site0 = idx_up[wid * N + lane];
    const int site1 = idx_dn[wid * N + lane];

    float l2sum = 0.0f;                // sum log2|pivot| over both dets
    unsigned sbits = 0u;               // xor of pivot sign bits (uniform)
    int inv = 0;                       // inversion count (uniform)

    #pragma unroll 1
    for (int spin = 0; spin < 2; ++spin) {
        const int site = (spin == 0) ? site0 : site1;

        // lane i holds row i of the gathered matrix, in registers
        float a[N], b[N];
        {
            const float4* __restrict__ row =
                reinterpret_cast<const float4*>(U + (long)site * N);
            #pragma unroll
            for (int q = 0; q < N / 4; ++q) {
                float4 v = row[q];
                a[4*q+0]=v.x; a[4*q+1]=v.y; a[4*q+2]=v.z; a[4*q+3]=v.w;
            }
        }

        unsigned long long chosen = 0ull;
        bool alive = true;

        // prologue: pivot for step 0
        int ps = pivot_argmax(a[0], alive, lane);

        // 64 steps = 4 rolled blocks of 16, widths shrink 63/47/31/15
        lu_block16<63>(a, b, ps, alive, chosen, inv, sbits, l2sum, lane);
        lu_block16<47>(a, b, ps, alive, chosen, inv, sbits, l2sum, lane);
        lu_block16<31>(a, b, ps, alive, chosen, inv, sbits, l2sum, lane);
        lu_block16<15>(a, b, ps, alive, chosen, inv, sbits, l2sum, lane);
    }

    if (lane == 0) {
        const float sgn =
            (((sbits >> 31) ^ ((unsigned)inv & 1u)) != 0u) ? -1.0f : 1.0f;
        out[wid] = sgn;                                        // sign_up * sign_dn
        out[BATCH + wid] = l2sum * 0.69314718055994530942f;    // ln from log2
    }
}

extern "C" void kernel_launch(void* const* d_in, const int* in_sizes, int n_in,
                              void* d_out, int out_size, void* d_ws, size_t ws_size,
                              hipStream_t stream) {
    const float* U      = (const float*)d_in[0];
    const int*   idx_up = (const int*)d_in[1];
    const int*   idx_dn = (const int*)d_in[2];
    float* out = (float*)d_out;

    dim3 block(64);                  // one wave per block, 1 sample per wave
    dim3 grid(BATCH);                // 4096 waves, exact cover
    hipLaunchKernelGGL(restricted_det_kernel, grid, block, 0, stream,
                       U, idx_up, idx_dn, out);
}